// Round 5
// baseline (350.173 us; speedup 1.0000x reference)
//
#include <hip/hip_runtime.h>
#include <hip/hip_bf16.h>
#include <math.h>

#define N_BATCH 128
#define C_CH    512
#define HF      38
#define WF      38
#define K1      25088   // 512*49
#define NH      4096
#define NCLS    21
#define NBOX    80
#define STEPS1  784     // K1/32
#define STEPS2  128     // NH/32

typedef __attribute__((ext_vector_type(8))) short s16x8;
typedef __attribute__((ext_vector_type(4))) float f32x4;

// fp32 -> 3x bf16 split (RNE): x ~= b0+b1+b2, residual ~ |x|*2^-25
__device__ __forceinline__ unsigned short bf_rne(float x) {
  unsigned u = __float_as_uint(x);
  return (unsigned short)((u + 0x7FFFu + ((u >> 16) & 1u)) >> 16);
}
__device__ __forceinline__ float bf2f(unsigned short b) {
  return __uint_as_float(((unsigned)b) << 16);
}
__device__ __forceinline__ void split3(float x, unsigned short& q0,
                                       unsigned short& q1, unsigned short& q2) {
  q0 = bf_rne(x); float r1 = x - bf2f(q0);
  q1 = bf_rne(r1); float r2 = r1 - bf2f(q1);
  q2 = bf_rne(r2);
}

__device__ __forceinline__ void gload16(const void* g, void* l) {
  __builtin_amdgcn_global_load_lds(
      (const __attribute__((address_space(1))) unsigned int*)g,
      (__attribute__((address_space(3))) unsigned int*)l, 16, 0, 0);
}

// ---------------------------------------------------------------------------
// Kernel 1: ROI crop + adaptive 7x7 maxpool -> flat fp32 [128][K1]
// ---------------------------------------------------------------------------
__global__ __launch_bounds__(256) void pool_kernel(
    const float* __restrict__ x, const int* __restrict__ rp,
    float* __restrict__ flat) {
  const int n = blockIdx.y, cb = blockIdx.x, tid = threadIdx.x;
  const int r = rp[n*4+0], c = rp[n*4+1], w = rp[n*4+2], h = rp[n*4+3];
  __shared__ float tile[8][24][25];
  const int ch = tid >> 5, l32 = tid & 31;
  const float* xc = x + (((size_t)(n*C_CH + cb*8 + ch))*HF + c)*WF + r;
  for (int y = 0; y < h; ++y)
    for (int xx = l32; xx < w; xx += 32)
      tile[ch][y][xx] = xc[y*WF + xx];
  __syncthreads();
  for (int o = tid; o < 8*49; o += 256) {
    int ch2 = o / 49, ij = o - ch2*49, i = ij / 7, j = ij - i*7;
    int rs = (i*h)/7, re = ((i+1)*h + 6)/7;
    int cs = (j*w)/7, ce = ((j+1)*w + 6)/7;
    float m = -INFINITY;
    for (int y = rs; y < re; ++y)
      for (int xx = cs; xx < ce; ++xx)
        m = fmaxf(m, tile[ch2][y][xx]);
    flat[(size_t)n*K1 + (cb*8+ch2)*49 + ij] = m;
  }
}

// ---------------------------------------------------------------------------
// Kernel 2: fp32 [128][ld] -> 3 bf16 planes in MFMA fragment order.
// ---------------------------------------------------------------------------
__global__ __launch_bounds__(256) void convert_kernel(
    const float* __restrict__ flat, unsigned short* __restrict__ Asw, int ld) {
  const int S = blockIdx.x, t = threadIdx.x;
  const int mt = t >> 5, g2 = (t >> 4) & 1, mlo = t & 15;
  #pragma unroll
  for (int gg = 0; gg < 2; ++gg) {
    const int g = g2 + gg*2;
    const float* src = flat + (size_t)(mt*16 + mlo)*ld + S*32 + g*8;
    float v[8];
    *(float4*)&v[0] = *(const float4*)src;
    *(float4*)&v[4] = *(const float4*)(src + 4);
    unsigned short q[3][8];
    #pragma unroll
    for (int e = 0; e < 8; ++e) split3(v[e], q[0][e], q[1][e], q[2][e]);
    size_t base = (size_t)S*12288 + mt*512 + (size_t)(g*16 + mlo)*8;
    #pragma unroll
    for (int p = 0; p < 3; ++p) {
      ushort4 lo; lo.x=q[p][0]; lo.y=q[p][1]; lo.z=q[p][2]; lo.w=q[p][3];
      ushort4 hi; hi.x=q[p][4]; hi.y=q[p][5]; hi.z=q[p][6]; hi.w=q[p][7];
      *(ushort4*)(Asw + base + p*4096)     = lo;
      *(ushort4*)(Asw + base + p*4096 + 4) = hi;
    }
  }
}

// ---------------------------------------------------------------------------
// Kernel 3: barrier-free split-K MFMA GEMM. BM=128, BN=128, BK=32, 4 waves.
// Each wave owns cols [wv*32, wv*32+32) and has a PRIVATE double-buffered
// 4KB LDS B-slice [32 k][32 col'] staged via global_load_lds with
// pre-swizzled source cols (col' = col ^ 8*(row>>3)) so fragment reads are
// <=2-way banked (free). Sync = counted `s_waitcnt vmcnt(4)` only (T4);
// no __syncthreads in the whole kernel (no barrier drain, free wave slip).
// A: direct global->register (fragment-ordered planes, L2-resident).
// ---------------------------------------------------------------------------
__global__ __launch_bounds__(256, 2) void gemm_v4(
    const unsigned short* __restrict__ Asw, const float* __restrict__ B,
    float* __restrict__ part, const int nsteps) {
  __shared__ float Bsm[4][2][32][32];    // [wave][dbuf][k][col'] = 32 KB
  const int tid = threadIdx.x, lane = tid & 63, wv = tid >> 6;
  const int nb = blockIdx.x, ks = blockIdx.y;
  const int l15 = lane & 15, g = lane >> 4;
  const unsigned short* Ab = Asw + (size_t)ks * nsteps * 12288;
  // stage source: lane -> row (lane>>3), col-group (lane&7), chunk i covers
  // rows i*8..i*8+7; source col pre-swizzled: ((lane&7) ^ (2*i)) * 4.
  const int srow = lane >> 3, scol = lane & 7;
  const float* Bg = B + ((size_t)ks*nsteps*32 + srow)*NH
                  + (size_t)nb*128 + wv*32;
  float* lds0 = &Bsm[wv][0][0][0];

  f32x4 acc[8][2];
  #pragma unroll
  for (int i = 0; i < 8; ++i)
    #pragma unroll
    for (int j = 0; j < 2; ++j) acc[i][j] = (f32x4){0.f, 0.f, 0.f, 0.f};

  // prologue: stage step 0 into buf 0
  #pragma unroll
  for (int i = 0; i < 4; ++i)
    gload16(Bg + (size_t)(i*8)*NH + ((scol ^ (2*i)) << 2), lds0 + i*256);

  int cur = 0;
  for (int s = 0; s < nsteps; ++s) {
    if (s + 1 < nsteps) {   // stage next step into other buffer, then wait
      const float* Bn = Bg + (size_t)(s+1)*32*NH;
      float* ldsn = lds0 + (cur ^ 1)*1024;
      #pragma unroll
      for (int i = 0; i < 4; ++i)
        gload16(Bn + (size_t)(i*8)*NH + ((scol ^ (2*i)) << 2), ldsn + i*256);
      asm volatile("s_waitcnt vmcnt(4)" ::: "memory");  // drain all but new 4
    } else {
      asm volatile("s_waitcnt vmcnt(0)" ::: "memory");
    }
    // B fragments: lane needs B[k=g*8+e][col=nt*16+l15] ->
    // LDS(row=g*8+e, col' = col ^ (8g)); <=2-way banks.
    const float* bb = lds0 + cur*1024;
    s16x8 bf0[2], bf1[2], bf2[2];
    #pragma unroll
    for (int nt = 0; nt < 2; ++nt) {
      #pragma unroll
      for (int e = 0; e < 8; ++e) {
        float xv = bb[(g*8 + e)*32 + ((nt*16 + l15) ^ (g*8))];
        unsigned short q0, q1, q2; split3(xv, q0, q1, q2);
        bf0[nt][e] = (short)q0; bf1[nt][e] = (short)q1; bf2[nt][e] = (short)q2;
      }
    }
    const unsigned short* As = Ab + (size_t)s*12288 + lane*8;
    s16x8 a0n = *(const s16x8*)(As);
    s16x8 a1n = *(const s16x8*)(As + 4096);
    s16x8 a2n = *(const s16x8*)(As + 8192);
    #pragma unroll
    for (int mt = 0; mt < 8; ++mt) {
      const s16x8 a0 = a0n, a1 = a1n, a2 = a2n;
      if (mt < 7) {
        a0n = *(const s16x8*)(As + (mt+1)*512);
        a1n = *(const s16x8*)(As + 4096 + (mt+1)*512);
        a2n = *(const s16x8*)(As + 8192 + (mt+1)*512);
      }
      #pragma unroll
      for (int nt = 0; nt < 2; ++nt) {
        f32x4 cc = acc[mt][nt];
        cc = __builtin_amdgcn_mfma_f32_16x16x32_bf16(a0, bf0[nt], cc, 0, 0, 0);
        cc = __builtin_amdgcn_mfma_f32_16x16x32_bf16(a0, bf1[nt], cc, 0, 0, 0);
        cc = __builtin_amdgcn_mfma_f32_16x16x32_bf16(a1, bf0[nt], cc, 0, 0, 0);
        cc = __builtin_amdgcn_mfma_f32_16x16x32_bf16(a0, bf2[nt], cc, 0, 0, 0);
        cc = __builtin_amdgcn_mfma_f32_16x16x32_bf16(a1, bf1[nt], cc, 0, 0, 0);
        cc = __builtin_amdgcn_mfma_f32_16x16x32_bf16(a2, bf0[nt], cc, 0, 0, 0);
        acc[mt][nt] = cc;
      }
    }
    cur ^= 1;
  }
  float* Pb = part + (size_t)ks*N_BATCH*NH + (size_t)nb*128 + wv*32;
  #pragma unroll
  for (int mt = 0; mt < 8; ++mt)
    #pragma unroll
    for (int nt = 0; nt < 2; ++nt)
      #pragma unroll
      for (int rr = 0; rr < 4; ++rr)
        Pb[(size_t)(mt*16 + g*4 + rr)*NH + nt*16 + l15] = acc[mt][nt][rr];
}

// ---------------------------------------------------------------------------
// Kernel 4: reduce split-K partials + bias + relu -> fp32 [128][4096]
// ---------------------------------------------------------------------------
__global__ __launch_bounds__(256) void reduce_k(
    const float* __restrict__ part, const float* __restrict__ bias,
    float* __restrict__ outp, int KS) {
  const int idx = blockIdx.x*256 + threadIdx.x;
  float4 s = ((const float4*)part)[idx];
  for (int k2 = 1; k2 < KS; ++k2) {
    float4 p = ((const float4*)part)[(size_t)k2*131072 + idx];
    s.x += p.x; s.y += p.y; s.z += p.z; s.w += p.w;
  }
  float4 bv = ((const float4*)bias)[idx & 1023];
  float4 o;
  o.x = fmaxf(s.x + bv.x, 0.f); o.y = fmaxf(s.y + bv.y, 0.f);
  o.z = fmaxf(s.z + bv.z, 0.f); o.w = fmaxf(s.w + bv.w, 0.f);
  ((float4*)outp)[idx] = o;
}

// ---------------------------------------------------------------------------
// Kernel 5a: transpose Wcls|Wbox into WT[101][4096]
// ---------------------------------------------------------------------------
__global__ __launch_bounds__(256) void head_transpose(
    const float* __restrict__ Wcls, const float* __restrict__ Wbox,
    float* __restrict__ WT) {
  const int c = blockIdx.x;
  const float* src; int stride;
  if (c < NCLS) { src = Wcls + c; stride = NCLS; }
  else          { src = Wbox + (c - NCLS); stride = NBOX; }
  for (int k = threadIdx.x; k < NH; k += 256)
    WT[(size_t)c*NH + k] = src[(size_t)k*stride];
}

// ---------------------------------------------------------------------------
// Kernel 5b: one wave per (n, col): float4 dot over K=4096 + shuffle reduce
// ---------------------------------------------------------------------------
__global__ __launch_bounds__(256) void head_dots(
    const float* __restrict__ h2, const float* __restrict__ WT,
    float* __restrict__ hout) {
  const int n = blockIdx.y;
  const int wv = threadIdx.x >> 6, lane = threadIdx.x & 63;
  const int c = blockIdx.x * 4 + wv;
  if (c >= NCLS + NBOX) return;
  const float4* hp = (const float4*)(h2 + (size_t)n*NH);
  const float4* wp = (const float4*)(WT + (size_t)c*NH);
  float s0=0.f, s1=0.f, s2=0.f, s3=0.f;
  #pragma unroll
  for (int it = 0; it < 16; ++it) {
    float4 a = hp[it*64 + lane];
    float4 b = wp[it*64 + lane];
    s0 = fmaf(a.x, b.x, s0); s1 = fmaf(a.y, b.y, s1);
    s2 = fmaf(a.z, b.z, s2); s3 = fmaf(a.w, b.w, s3);
  }
  float v = (s0 + s1) + (s2 + s3);
  #pragma unroll
  for (int m = 32; m >= 1; m >>= 1) v += __shfl_xor(v, m, 64);
  if (lane == 0) hout[n*128 + c] = v;
}

// ---------------------------------------------------------------------------
// Kernel 5c: softmax(21) + bbox(80) from stored dots.
// ---------------------------------------------------------------------------
__global__ __launch_bounds__(128) void head_final(
    const float* __restrict__ hout, const int* __restrict__ rp,
    float* __restrict__ out) {
  const int n = blockIdx.x, tid = threadIdx.x;
  __shared__ float logits[NCLS];
  __shared__ float red[2];
  if (tid < NCLS) logits[tid] = hout[n*128 + tid];
  __syncthreads();
  if (tid == 0) {
    float m = logits[0];
    for (int i = 1; i < NCLS; ++i) m = fmaxf(m, logits[i]);
    float s = 0.f;
    for (int i = 0; i < NCLS; ++i) s += expf(logits[i] - m);
    red[0] = m; red[1] = s;
  }
  __syncthreads();
  if (tid < NCLS) {
    out[(size_t)n*NCLS + tid] = expf(logits[tid] - red[0]) / red[1];
  } else if (tid < NCLS + NBOX) {
    const int j = tid - NCLS;
    const float t  = hout[n*128 + tid];
    const float rf = (float)rp[n*4+0];
    const float cf = (float)rp[n*4+1];
    const float wf = (float)rp[n*4+2];
    const float hf = (float)rp[n*4+3];
    float p;
    switch (j & 3) {
      case 0:  p = ceilf (__fmul_rn(__fadd_rn(__fmul_rn(wf, t), rf), 16.f)) - 1.f; break;
      case 1:  p = ceilf (__fmul_rn(__fadd_rn(__fmul_rn(hf, t), cf), 16.f)) - 1.f; break;
      case 2:  p = floorf(__fmul_rn(__fmul_rn(wf, expf(t)), 16.f)) + 1.f; break;
      default: p = floorf(__fmul_rn(__fmul_rn(hf, expf(t)), 16.f)) + 1.f; break;
    }
    out[(size_t)N_BATCH*NCLS + (size_t)n*NBOX + j] = p;
  }
}

// ---------------------------------------------------------------------------
extern "C" void kernel_launch(void* const* d_in, const int* in_sizes, int n_in,
                              void* d_out, int out_size, void* d_ws, size_t ws_size,
                              hipStream_t stream) {
  const float* x    = (const float*)d_in[0];
  const int*   rp   = (const int*)  d_in[1];
  const float* W1   = (const float*)d_in[2];
  const float* b1   = (const float*)d_in[3];
  const float* W2   = (const float*)d_in[4];
  const float* b2   = (const float*)d_in[5];
  const float* Wcls = (const float*)d_in[6];
  const float* Wbox = (const float*)d_in[7];
  float* out = (float*)d_out;

  // ws: flat | Asw1 | Asw2 | h1f | h2f | WT | hout | part
  char* wp = (char*)d_ws;
  float* flat = (float*)wp;           wp += (size_t)N_BATCH*K1*4;
  unsigned short* Asw1 = (unsigned short*)wp; wp += (size_t)STEPS1*24576;
  unsigned short* Asw2 = (unsigned short*)wp; wp += (size_t)STEPS2*24576;
  float* h1f = (float*)wp;            wp += (size_t)N_BATCH*NH*4;
  float* h2f = (float*)wp;            wp += (size_t)N_BATCH*NH*4;
  float* WT  = (float*)wp;            wp += (size_t)(NCLS+NBOX)*NH*4;
  float* hout = (float*)wp;           wp += (size_t)N_BATCH*128*4;
  float* part = (float*)wp;
  const size_t fixed = (size_t)(wp - (char*)d_ws);
  const size_t slab = (size_t)N_BATCH*NH*4;       // 2 MB per partial
  int KS = 16;
  if (fixed + 16*slab > ws_size) KS = 8;
  if (fixed + (size_t)KS*slab > ws_size) KS = 4;

  pool_kernel<<<dim3(64, 128), 256, 0, stream>>>(x, rp, flat);
  convert_kernel<<<dim3(STEPS1), 256, 0, stream>>>(flat, Asw1, K1);
  head_transpose<<<dim3(NCLS + NBOX), 256, 0, stream>>>(Wcls, Wbox, WT);

  gemm_v4<<<dim3(32, KS), 256, 0, stream>>>(Asw1, W1, part, STEPS1/KS);
  reduce_k<<<dim3(512), 256, 0, stream>>>(part, b1, h1f, KS);
  convert_kernel<<<dim3(STEPS2), 256, 0, stream>>>(h1f, Asw2, NH);

  gemm_v4<<<dim3(32, KS), 256, 0, stream>>>(Asw2, W2, part, STEPS2/KS);
  reduce_k<<<dim3(512), 256, 0, stream>>>(part, b2, h2f, KS);

  head_dots<<<dim3(26, 128), 256, 0, stream>>>(h2f, WT, hout);
  head_final<<<dim3(128), 128, 0, stream>>>(hout, rp, out);
}